// Round 2
// baseline (93.804 us; speedup 1.0000x reference)
//
#include <hip/hip_runtime.h>
#include <stdint.h>

// MajFC: out[b,c] = 2.25 * sum_g clip(sum_{k<3} sign(x[b,3g+k])*sign(w[c,3g+k]), -1, 1)
// Sign-only bitplanes (absmax 0.0 verified): t = px ^ pw,
// clip(group) = 1 - 2*maj(t0,t1,t2), out = 2304 - 4.5*popc_total.
//
// Permutation trick: element e = 768q + 12l + 3j + k -> plane [q][3j+k] bit l,
// applied identically to x and w rows, leaves the popc-sum invariant.
//
// R10: SINGLE self-contained dispatch (no workspace, no fences, no cross-block
// dependency). Evidence: R8->R9 moved structure by whole-µs amounts while
// dur_us sat at 70-73, and our kernels never appear in rocprof top-5 (each
// <41 µs; harness fills run 42 µs @ 6.4 TB/s) => measurement is dominated by
// per-dispatch fixed overhead. Only lever left: dispatch count (2 -> 1).
//   - 256 blocks (1/CU), tile = 32 b-rows x 32 c-rows (minimizes redundant
//     raw reads: x*32 + w*8 ~= 200 MB, L2-resident by XCD-aware tile map:
//     XCD r = blockIdx%8 owns ct in [4r,4r+4) -> per-XCD set ~4.7 MB).
//   - Each block ballot-packs its x-tile and w-tile into LDS (2x32x49 u64,
//     +1 u64 row pad -> 2-way bank conflict = free), then 1 b x 4 c per thread.

#define C_IN  3072
#define C_OUT 1024
#define BT 32
#define CT 32
#define PSTR 49   // u64 per packed row: 48 planes + 1 pad

__global__ __launch_bounds__(256) void majfc_one(const float* __restrict__ x,
                                                 const float* __restrict__ w,
                                                 float* __restrict__ out) {
    __shared__ uint64_t xp[BT][PSTR];
    __shared__ uint64_t wp[CT][PSTR];

    const int tid  = threadIdx.x;
    const int lane = tid & 63;
    const int wv   = tid >> 6;

    // XCD-aware tile map (bijective): r=bid&7 -> ct=r*4+(s&3), bt=s>>2
    const int r  = blockIdx.x & 7;
    const int s  = blockIdx.x >> 3;
    const int ct = r * 4 + (s & 3);
    const int bt = s >> 2;
    const int b0 = bt * BT;
    const int c0 = ct * CT;

    // ---- pack phase: 256 wave-jobs (row x q), 64 per wave.
    // wave0: x rows 0..15 | wave1: x rows 16..31 | wave2: w 0..15 | wave3: w 16..31
    {
        const float* base = (wv & 2) ? (w + (size_t)c0 * C_IN) : (x + (size_t)b0 * C_IN);
        uint64_t (*dst)[PSTR] = (wv & 2) ? wp : xp;
        const int row0 = (wv & 1) * 16;
#pragma unroll 4
        for (int i = 0; i < 64; ++i) {
            const int row = row0 + (i >> 2);
            const int q   = i & 3;
            const float4* s4 = (const float4*)(base + (size_t)row * C_IN + q * 768 + 12 * lane);
            float4 f0 = s4[0], f1 = s4[1], f2 = s4[2];
            uint64_t pl0  = __ballot(f0.x > 0.0f);
            uint64_t pl1  = __ballot(f0.y > 0.0f);
            uint64_t pl2  = __ballot(f0.z > 0.0f);
            uint64_t pl3  = __ballot(f0.w > 0.0f);
            uint64_t pl4  = __ballot(f1.x > 0.0f);
            uint64_t pl5  = __ballot(f1.y > 0.0f);
            uint64_t pl6  = __ballot(f1.z > 0.0f);
            uint64_t pl7  = __ballot(f1.w > 0.0f);
            uint64_t pl8  = __ballot(f2.x > 0.0f);
            uint64_t pl9  = __ballot(f2.y > 0.0f);
            uint64_t pl10 = __ballot(f2.z > 0.0f);
            uint64_t pl11 = __ballot(f2.w > 0.0f);
            if (lane == 0) {
                uint64_t* d = &dst[row][q * 12];
                d[0] = pl0;  d[1] = pl1;  d[2]  = pl2;  d[3]  = pl3;
                d[4] = pl4;  d[5] = pl5;  d[6]  = pl6;  d[7]  = pl7;
                d[8] = pl8;  d[9] = pl9;  d[10] = pl10; d[11] = pl11;
            }
        }
    }
    __syncthreads();

    // ---- compute phase: thread = (b_local, c-quad)
    const int bl = tid & 31;
    const int cg = tid >> 5;          // 0..7 -> c_local = cg*4 + jj
    int acc[4] = {0, 0, 0, 0};
#pragma unroll
    for (int q = 0; q < 4; ++q) {
        uint64_t X[12];
#pragma unroll
        for (int m = 0; m < 12; ++m) X[m] = xp[bl][q * 12 + m];
#pragma unroll
        for (int jj = 0; jj < 4; ++jj) {
            const uint64_t* W = &wp[cg * 4 + jj][q * 12];
#pragma unroll
            for (int j = 0; j < 4; ++j) {
                uint64_t t0 = X[3 * j + 0] ^ W[3 * j + 0];
                uint64_t t1 = X[3 * j + 1] ^ W[3 * j + 1];
                uint64_t t2 = X[3 * j + 2] ^ W[3 * j + 2];
                acc[jj] += __popcll((t0 & t1) | (t2 & (t0 | t1)));
            }
        }
    }
    float4 res;
    res.x = 2304.0f - 4.5f * (float)acc[0];
    res.y = 2304.0f - 4.5f * (float)acc[1];
    res.z = 2304.0f - 4.5f * (float)acc[2];
    res.w = 2304.0f - 4.5f * (float)acc[3];
    *(float4*)(out + (size_t)(b0 + bl) * C_OUT + c0 + cg * 4) = res;
}

extern "C" void kernel_launch(void* const* d_in, const int* in_sizes, int n_in,
                              void* d_out, int out_size, void* d_ws, size_t ws_size,
                              hipStream_t stream) {
    const float* x = (const float*)d_in[0];   // [256, 3072] f32
    const float* w = (const float*)d_in[1];   // [1024, 3072] f32
    float* out = (float*)d_out;               // [256, 1024] f32
    (void)d_ws; (void)ws_size;

    majfc_one<<<256, 256, 0, stream>>>(x, w, out);
}

// Round 3
// 77.426 us; speedup vs baseline: 1.2115x; 1.2115x over previous
//
#include <hip/hip_runtime.h>
#include <stdint.h>

// MajFC: out[b,c] = 2.25 * sum_g clip(sum_{k<3} sign(x[b,3g+k])*sign(w[c,3g+k]), -1, 1)
// Sign-only bitplanes (absmax 0.0 verified): t = px ^ pw,
// clip(group) = 1 - 2*maj(t0,t1,t2), out = 2304 - 4.5*popc_total.
//
// Permutation trick: element e = 768q + 12l + 3j + k -> plane [q][3j+k] bit l,
// applied identically to x and w rows, leaves the popc-sum invariant.
//
// R11: keep R10's single self-contained dispatch (it isolated the ~47 µs harness
// floor: 268 MB ws poison fill @42 µs + launch), fix its latency-boundedness.
// R10 counters: 47 µs kernel, BW 400 GB/s (5%), VALUBusy 7.7%, Occupancy 9.4%
// => 200 MB of redundant raw reads served at 4.2 TB/s with only 4 waves/CU.
// Changes:
//   - 1024-thread blocks (16 waves/CU, 4x TLP; pack chain 64 -> 16 iters/wave).
//   - compute: 1 output/thread; cl in low lane bits => X reads half-wave
//     broadcast, W reads stride-392B (even banks, 2-way = free), out stores
//     coalesced 128 B/half-wave (R10 scattered them at 4 KB stride).
//   - tile stays 32b x 32c, 256 blocks, XCD-aware map (XCD r owns ct in
//     [4r,4r+4): per-XCD working set ~4.7 MB, mostly L2-resident, L3 backstop).

#define C_IN  3072
#define C_OUT 1024
#define BT 32
#define CT 32
#define PSTR 49   // u64 per packed row: 48 planes + 1 pad (392 B: even banks, 2-way free)

__global__ __launch_bounds__(1024) void majfc_one(const float* __restrict__ x,
                                                  const float* __restrict__ w,
                                                  float* __restrict__ out) {
    __shared__ uint64_t xp[BT][PSTR];
    __shared__ uint64_t wp[CT][PSTR];

    const int tid  = threadIdx.x;
    const int lane = tid & 63;
    const int wv   = tid >> 6;         // 0..15

    // XCD-aware tile map (bijective): r=bid&7 -> ct=r*4+(s&3), bt=s>>2
    const int r  = blockIdx.x & 7;
    const int s  = blockIdx.x >> 3;
    const int ct = r * 4 + (s & 3);
    const int bt = s >> 2;
    const int b0 = bt * BT;
    const int c0 = ct * CT;

    // ---- pack phase: 256 wave-jobs (row x q), 16 per wave, consecutive jobs
    // spread across waves so concurrent reads cover contiguous memory.
#pragma unroll 4
    for (int i = 0; i < 16; ++i) {
        const int h   = i * 16 + wv;          // 0..255
        const int row = (h & 127) >> 2;       // 0..31
        const int q   = h & 3;
        const float* src = ((h < 128) ? (x + (size_t)(b0 + row) * C_IN)
                                      : (w + (size_t)(c0 + row) * C_IN))
                           + q * 768 + 12 * lane;
        const float4* s4 = (const float4*)src;
        float4 f0 = s4[0], f1 = s4[1], f2 = s4[2];
        uint64_t pl0  = __ballot(f0.x > 0.0f);
        uint64_t pl1  = __ballot(f0.y > 0.0f);
        uint64_t pl2  = __ballot(f0.z > 0.0f);
        uint64_t pl3  = __ballot(f0.w > 0.0f);
        uint64_t pl4  = __ballot(f1.x > 0.0f);
        uint64_t pl5  = __ballot(f1.y > 0.0f);
        uint64_t pl6  = __ballot(f1.z > 0.0f);
        uint64_t pl7  = __ballot(f1.w > 0.0f);
        uint64_t pl8  = __ballot(f2.x > 0.0f);
        uint64_t pl9  = __ballot(f2.y > 0.0f);
        uint64_t pl10 = __ballot(f2.z > 0.0f);
        uint64_t pl11 = __ballot(f2.w > 0.0f);
        if (lane == 0) {
            uint64_t* d = (h < 128) ? &xp[row][q * 12] : &wp[row][q * 12];
            d[0] = pl0;  d[1] = pl1;  d[2]  = pl2;  d[3]  = pl3;
            d[4] = pl4;  d[5] = pl5;  d[6]  = pl6;  d[7]  = pl7;
            d[8] = pl8;  d[9] = pl9;  d[10] = pl10; d[11] = pl11;
        }
    }
    __syncthreads();

    // ---- compute phase: thread = (b_local = tid>>5, c_local = tid&31)
    // X: half-wave-uniform LDS broadcast; W: 32 distinct rows, 2-way free.
    const int cl = tid & 31;
    const int bl = tid >> 5;
    int acc = 0;
#pragma unroll
    for (int q = 0; q < 4; ++q) {
        uint64_t X[12], W[12];
#pragma unroll
        for (int m = 0; m < 12; ++m) {
            X[m] = xp[bl][q * 12 + m];
            W[m] = wp[cl][q * 12 + m];
        }
#pragma unroll
        for (int j = 0; j < 4; ++j) {
            uint64_t t0 = X[3 * j + 0] ^ W[3 * j + 0];
            uint64_t t1 = X[3 * j + 1] ^ W[3 * j + 1];
            uint64_t t2 = X[3 * j + 2] ^ W[3 * j + 2];
            acc += __popcll((t0 & t1) | (t2 & (t0 | t1)));
        }
    }
    out[(size_t)(b0 + bl) * C_OUT + c0 + cl] = 2304.0f - 4.5f * (float)acc;
}

extern "C" void kernel_launch(void* const* d_in, const int* in_sizes, int n_in,
                              void* d_out, int out_size, void* d_ws, size_t ws_size,
                              hipStream_t stream) {
    const float* x = (const float*)d_in[0];   // [256, 3072] f32
    const float* w = (const float*)d_in[1];   // [1024, 3072] f32
    float* out = (float*)d_out;               // [256, 1024] f32
    (void)d_ws; (void)ws_size;

    majfc_one<<<256, 1024, 0, stream>>>(x, w, out);
}

// Round 5
// 76.343 us; speedup vs baseline: 1.2287x; 1.0142x over previous
//
#include <hip/hip_runtime.h>
#include <stdint.h>

// MajFC: out[b,c] = 2.25 * sum_g clip(sum_{k<3} sign(x[b,3g+k])*sign(w[c,3g+k]), -1, 1)
// Sign-only bitplanes (absmax 0.0 verified): t = px ^ pw,
// clip(group) = 1 - 2*maj(t0,t1,t2), out = 2304 - 4.5*popc_total.
//
// Permutation trick: element e = 768q + 12l + 3j + k -> plane [q][3j+k] bit l,
// applied identically to x and w rows, leaves the popc-sum invariant.
//
// R13 == R12 resubmitted (R12 bench failed on container acquisition, not the
// kernel). Single dispatch (R10/R11), 1024 threads (R11), ONE change vs R11:
// K-PHASED pack order. R11 served its 196 MB of redundant raw reads at
// 6.5 TB/s (= L3-class rate): all 16 waves touched all 4 K-quarters of all
// 64 rows at once -> instantaneous per-XCD footprint 4.6 MB > 4.19 MiB L2
// -> LRU thrash, reads fell through to L3. Reorder: all waves sweep
// K-quarter q together (q = i>>2) -> per-phase per-XCD footprint ~1.15 MB
// << L2, cross-block line sharing (8 blocks/XCD per w-row, 4 per x-row)
// becomes L2 hits. Predicted pack 30 -> ~8 µs, total 77 -> ~57-62.

#define C_IN  3072
#define C_OUT 1024
#define BT 32
#define CT 32
#define PSTR 49   // u64 per packed row: 48 planes + 1 pad (392 B: even banks, 2-way free)

__global__ __launch_bounds__(1024) void majfc_one(const float* __restrict__ x,
                                                  const float* __restrict__ w,
                                                  float* __restrict__ out) {
    __shared__ uint64_t xp[BT][PSTR];
    __shared__ uint64_t wp[CT][PSTR];

    const int tid  = threadIdx.x;
    const int lane = tid & 63;
    const int wv   = tid >> 6;         // 0..15

    // XCD-aware tile map (bijective): r=bid&7 -> ct=r*4+(s&3), bt=s>>2
    const int r  = blockIdx.x & 7;
    const int s  = blockIdx.x >> 3;
    const int ct = r * 4 + (s & 3);
    const int bt = s >> 2;
    const int b0 = bt * BT;
    const int c0 = ct * CT;

    // ---- pack phase: 256 wave-jobs = (64 combined rows) x (4 K-quarters).
    // K-quarter q is swept by ALL waves during iters [4q, 4q+4) -> small,
    // shared, L2-resident phase footprint. x/w select is per-iteration
    // compile-time uniform (rowc<32 <=> (i&3)<2).
#pragma unroll 4
    for (int i = 0; i < 16; ++i) {
        const int q    = i >> 2;
        const int rowc = (i & 3) * 16 + wv;      // 0..63; <32 -> x, else w
        const float* src = ((rowc < 32) ? (x + (size_t)(b0 + rowc) * C_IN)
                                        : (w + (size_t)(c0 + rowc - 32) * C_IN))
                           + q * 768 + 12 * lane;
        const float4* s4 = (const float4*)src;
        float4 f0 = s4[0], f1 = s4[1], f2 = s4[2];
        uint64_t pl0  = __ballot(f0.x > 0.0f);
        uint64_t pl1  = __ballot(f0.y > 0.0f);
        uint64_t pl2  = __ballot(f0.z > 0.0f);
        uint64_t pl3  = __ballot(f0.w > 0.0f);
        uint64_t pl4  = __ballot(f1.x > 0.0f);
        uint64_t pl5  = __ballot(f1.y > 0.0f);
        uint64_t pl6  = __ballot(f1.z > 0.0f);
        uint64_t pl7  = __ballot(f1.w > 0.0f);
        uint64_t pl8  = __ballot(f2.x > 0.0f);
        uint64_t pl9  = __ballot(f2.y > 0.0f);
        uint64_t pl10 = __ballot(f2.z > 0.0f);
        uint64_t pl11 = __ballot(f2.w > 0.0f);
        if (lane == 0) {
            uint64_t* d = (rowc < 32) ? &xp[rowc][q * 12] : &wp[rowc - 32][q * 12];
            d[0] = pl0;  d[1] = pl1;  d[2]  = pl2;  d[3]  = pl3;
            d[4] = pl4;  d[5] = pl5;  d[6]  = pl6;  d[7]  = pl7;
            d[8] = pl8;  d[9] = pl9;  d[10] = pl10; d[11] = pl11;
        }
    }
    __syncthreads();

    // ---- compute phase: thread = (b_local = tid>>5, c_local = tid&31)
    // X: half-wave-uniform LDS broadcast; W: 2-way (free) bank aliasing.
    const int cl = tid & 31;
    const int bl = tid >> 5;
    int acc = 0;
#pragma unroll
    for (int q = 0; q < 4; ++q) {
        uint64_t X[12], W[12];
#pragma unroll
        for (int m = 0; m < 12; ++m) {
            X[m] = xp[bl][q * 12 + m];
            W[m] = wp[cl][q * 12 + m];
        }
#pragma unroll
        for (int j = 0; j < 4; ++j) {
            uint64_t t0 = X[3 * j + 0] ^ W[3 * j + 0];
            uint64_t t1 = X[3 * j + 1] ^ W[3 * j + 1];
            uint64_t t2 = X[3 * j + 2] ^ W[3 * j + 2];
            acc += __popcll((t0 & t1) | (t2 & (t0 | t1)));
        }
    }
    out[(size_t)(b0 + bl) * C_OUT + c0 + cl] = 2304.0f - 4.5f * (float)acc;
}

extern "C" void kernel_launch(void* const* d_in, const int* in_sizes, int n_in,
                              void* d_out, int out_size, void* d_ws, size_t ws_size,
                              hipStream_t stream) {
    const float* x = (const float*)d_in[0];   // [256, 3072] f32
    const float* w = (const float*)d_in[1];   // [1024, 3072] f32
    float* out = (float*)d_out;               // [256, 1024] f32
    (void)d_ws; (void)ws_size;

    majfc_one<<<256, 1024, 0, stream>>>(x, w, out);
}